// Round 1
// baseline (695.612 us; speedup 1.0000x reference)
//
#include <hip/hip_runtime.h>
#include <stdint.h>

// IsoMaxPlusLossFirstPart: logits[b,k,h,w] = -|scale| * || xn(b,:,h,w) - pn(k,:) ||
// via quadratic expansion d2 = xx + pp - 2*dot, normalization folded into epilogue.
//
// Memory-bound: 512 MiB feature read + 38 MiB write -> ~87 us floor @ 6.3 TB/s.
// v2 strategy vs previous (689 us):
//  - 2 pixels/thread (float2) -> 1024 blocks -> 16 waves/CU (4/SIMD) for latency
//    hiding (was 512 blocks = 2 waves/SIMD, latency-bound).
//  - prototypes normalized+transposed [c][20] into workspace by a tiny prep
//    kernel; main loop reads them through an addrspace(4) (constant) pointer so
//    uniform accesses become s_load_* into SGPRs (scalar unit runs ahead) --
//    removes all 1280 ds_read_b128/wave + their lgkmcnt stalls, LDS usage -> 0.

namespace {
constexpr int kC     = 256;
constexpr int kK     = 19;
constexpr int kKP    = 20;           // padded K (80 B rows, 16B-aligned)
constexpr int kHW    = 128 * 256;    // 32768
constexpr int kBlock = 256;
constexpr int kPix   = 2;            // pixels per thread
}

// CK-style constant-address-space pointer: uniform loads select s_load (SMEM).
typedef __attribute__((address_space(4))) const float* cfp;

__global__ void proto_prep(const float* __restrict__ proto,
                           float* __restrict__ ws)
{
    float* pw = ws;               // [kC][kKP] normalized prototypes, transposed
    float* pp = ws + kC * kKP;    // [kK] sum(pn^2)
    const int tid  = threadIdx.x;
    const int lane = tid & 63;
    const int wv   = tid >> 6;    // wave 0..3

    for (int k = wv; k < kK; k += 4) {
        float v[4];
        float ss = 0.f;
        #pragma unroll
        for (int j = 0; j < 4; ++j) {
            v[j] = proto[k * kC + j * 64 + lane];   // coalesced across lanes
            ss = fmaf(v[j], v[j], ss);
        }
        #pragma unroll
        for (int m = 1; m < 64; m <<= 1)            // butterfly: all lanes get sum
            ss += __shfl_xor(ss, m, 64);
        const float inv = 1.0f / fmaxf(sqrtf(ss), 1e-12f);
        #pragma unroll
        for (int j = 0; j < 4; ++j)
            pw[(j * 64 + lane) * kKP + k] = v[j] * inv;
        if (lane == 0) pp[k] = ss * inv * inv;      // == sum(pn_normalized^2)
    }
    pw[tid * kKP + (kKP - 1)] = 0.f;                // zero the pad column (c = tid)
}

__global__ __launch_bounds__(kBlock, 4)
void isomax_main(const float* __restrict__ feat,
                 const float* __restrict__ ws,
                 const float* __restrict__ dscale,
                 float* __restrict__ out)
{
    const int tid  = threadIdx.x;
    const int gpix = (blockIdx.x * kBlock + tid) * kPix;  // flat pixel idx (even)
    const int b    = gpix >> 15;          // / kHW
    const int hw   = gpix & (kHW - 1);    // % kHW

    const float2* __restrict__ fp =
        (const float2*)(feat + (size_t)b * kC * kHW + hw);

    cfp pw = (cfp)(uintptr_t)ws;          // [kC][kKP] via scalar loads

    float2 xx = make_float2(0.f, 0.f);    // raw sum(x^2) per pixel
    float2 dot[kK];                        // raw x.pn per pixel
    #pragma unroll
    for (int k = 0; k < kK; ++k) dot[k] = make_float2(0.f, 0.f);

    for (int cc = 0; cc < kC; cc += 4) {
        float2 v[4];
        #pragma unroll
        for (int u = 0; u < 4; ++u)        // 4 independent 8B loads in flight
            v[u] = fp[(size_t)(cc + u) * (kHW / 2)];
        #pragma unroll
        for (int u = 0; u < 4; ++u) {
            const int c = cc + u;
            float p[kKP];
            #pragma unroll
            for (int q = 0; q < kKP; ++q)  // uniform -> s_load into SGPRs
                p[q] = pw[c * kKP + q];
            xx.x = fmaf(v[u].x, v[u].x, xx.x);
            xx.y = fmaf(v[u].y, v[u].y, xx.y);
            #pragma unroll
            for (int k = 0; k < kK; ++k) {
                dot[k].x = fmaf(p[k], v[u].x, dot[k].x);
                dot[k].y = fmaf(p[k], v[u].y, dot[k].y);
            }
        }
    }

    // ---- Epilogue: fold normalization, distance, scale ----
    const float ix  = 1.0f / fmaxf(sqrtf(xx.x), 1e-12f);
    const float iy  = 1.0f / fmaxf(sqrtf(xx.y), 1e-12f);
    const float xnx = xx.x * ix * ix;     // sum(xn^2), matches ref structure
    const float xny = xx.y * iy * iy;
    const float sc  = fabsf(dscale[0]);

    cfp pp = (cfp)(uintptr_t)(ws + kC * kKP);

    float2* op = (float2*)(out + (size_t)b * kK * kHW + hw);
    #pragma unroll
    for (int k = 0; k < kK; ++k) {
        const float ppk = pp[k];
        float2 o;
        o.x = -sc * sqrtf(fmaxf(xnx + ppk - 2.0f * dot[k].x * ix, 0.f));
        o.y = -sc * sqrtf(fmaxf(xny + ppk - 2.0f * dot[k].y * iy, 0.f));
        op[(size_t)k * (kHW / 2)] = o;     // coalesced along w per k
    }
}

extern "C" void kernel_launch(void* const* d_in, const int* in_sizes, int n_in,
                              void* d_out, int out_size, void* d_ws, size_t ws_size,
                              hipStream_t stream)
{
    const float* feat   = (const float*)d_in[0];
    const float* proto  = (const float*)d_in[1];
    const float* dscale = (const float*)d_in[2];
    float* out = (float*)d_out;
    float* ws  = (float*)d_ws;   // needs (256*20 + 19) floats ~ 20.6 KiB

    proto_prep<<<dim3(1), dim3(kBlock), 0, stream>>>(proto, ws);

    const int npix = in_sizes[0] / kC;               // B*H*W = 524288
    const dim3 grid(npix / (kBlock * kPix));         // 1024 blocks
    isomax_main<<<grid, dim3(kBlock), 0, stream>>>(feat, ws, dscale, out);
}